// Round 5
// baseline (398.082 us; speedup 1.0000x reference)
//
#include <hip/hip_runtime.h>
#include <hip/hip_bf16.h>

#define T_DIM 512
#define L_DIM 128

typedef _Float16 h2 __attribute__((ext_vector_type(2)));

#if defined(__has_builtin)
#if __has_builtin(__builtin_amdgcn_fdot2)
#define HAS_FDOT2 1
#endif
#endif

__device__ __forceinline__ float fdot2_acc(h2 a, h2 b, float c) {
#ifdef HAS_FDOT2
    return __builtin_amdgcn_fdot2(a, b, c, false);
#else
    return c + (float)a.x * (float)b.x + (float)a.y * (float)b.y;
#endif
}

__device__ __forceinline__ h2 pack_f16(float a, float b) {
    return __builtin_bit_cast(h2, __builtin_amdgcn_cvt_pkrtz(a, b));
}

__device__ __forceinline__ h2 uint_as_h2(unsigned int v) {
    return __builtin_bit_cast(h2, v);
}

// ONE WAVE PER CHAIN — no s_barrier anywhere in the step loop.
// Lane p owns labels j0=2p, j1=2p+1: holds both full E columns (f16, pre-
// scaled by 1/128) in 128 VGPRs and computes the complete 128-i dot for
// both labels (128 fdot2). State u (128 f16) lives in a 256 B double-
// buffered LDS image: one ds_write_b32 per lane (pair-packed), then 16
// same-address ds_read_b128 broadcasts next step. Wave-lockstep + explicit
// s_waitcnt lgkmcnt(0) replaces __syncthreads (which would also drain
// vmcnt and kill the feats prefetch).
//
// Multiplicative recurrence (round-4 numerics): u'_j = (Σ_i u_i Êij)·exp(f),
// scale tracked in S via u0-renorm every 16 steps; u0 is free in all lanes
// from the broadcast read (R[0].x).
__global__ __launch_bounds__(64, 1) void crf_fwd_kernel(
    const float* __restrict__ feats,
    const float* __restrict__ transfer,
    const int* __restrict__ target,
    const int* __restrict__ startp,
    const int* __restrict__ stopp,
    float* __restrict__ out)
{
    __shared__ unsigned int LdsU[2][64] __attribute__((aligned(16)));

    const int lane = threadIdx.x;       // 0..63, owns label pair (2p, 2p+1)
    const int p    = lane;
    const int j0   = p << 1;
    const int j1   = j0 | 1;
    const int b    = blockIdx.x;
    const int start = startp[0];
    const int stop  = stopp[0];
    const float* fbase = feats + (size_t)b * T_DIM * L_DIM;
    const float2* f2 = reinterpret_cast<const float2*>(fbase);
    const float LOG128 = 4.852030263919617f;

    // ---- one-time: both E columns, Ehat = exp(transfer)/128, in regs ----
    h2 E0[64], E1[64];
#pragma unroll
    for (int q = 0; q < 64; ++q) {
        const float2* r0 = reinterpret_cast<const float2*>(transfer + (2 * q) * L_DIM + j0);
        const float2* r1 = reinterpret_cast<const float2*>(transfer + (2 * q + 1) * L_DIM + j0);
        float2 e0 = *r0;   // (tr[2q][j0], tr[2q][j1])
        float2 e1 = *r1;   // (tr[2q+1][j0], tr[2q+1][j1])
        E0[q] = pack_f16(__expf(e0.x) * 0.0078125f, __expf(e1.x) * 0.0078125f);
        E1[q] = pack_f16(__expf(e0.y) * 0.0078125f, __expf(e1.y) * 0.0078125f);
    }
    const float trS0 = transfer[j0 * L_DIM + stop];
    const float trS1 = transfer[j1 * L_DIM + stop];

    // ---- init: u = exp(f_1 + tr[start] + f_2) ----
    {
        float2 f1v = f2[1 * 64 + p];
        float2 f2v = f2[2 * 64 + p];
        const float2* ts = reinterpret_cast<const float2*>(transfer + start * L_DIM + j0);
        float2 tsv = *ts;
        float v0 = f1v.x + f2v.x + tsv.x;
        float v1 = f1v.y + f2v.y + tsv.y;
        LdsU[0][p] = __builtin_bit_cast(unsigned int, pack_f16(__expf(v0), __expf(v1)));
    }
    float2 fa = f2[3 * 64 + p];   // f_{t+1} consumed at t=2
    float2 fb = f2[4 * 64 + p];
    float S = 0.f;

    int cur = 0;
    float accF0 = 0.f, accF1 = 0.f;

    for (int t = 2; t <= T_DIM - 1; ++t) {
        int tp = t + 3; if (tp > T_DIM - 1) tp = T_DIM - 1;
        float2 fnew = f2[tp * 64 + p];        // stays in flight (no vmcnt drain)
        float fe0 = __expf(fa.x);
        float fe1 = __expf(fa.y);

        // prior-iteration ds_write must be visible before this read
        asm volatile("s_waitcnt lgkmcnt(0)" ::: "memory");
        const uint4* P4 = reinterpret_cast<const uint4*>(&LdsU[cur][0]);
        uint4 R[16];
#pragma unroll
        for (int r = 0; r < 16; ++r) R[r] = P4[r];   // broadcast reads

        if ((t & 15) == 0) {                  // periodic renorm, off-path
            float u0 = (float)uint_as_h2(R[0].x).x;
            float rr = __builtin_amdgcn_rcpf(u0);
            S += __logf(u0);
            fe0 *= rr; fe1 *= rr;
        }

        float a0 = 0.f, a1 = 0.f, a2 = 0.f, a3 = 0.f;
        float c0 = 0.f, c1 = 0.f, c2 = 0.f, c3 = 0.f;
#pragma unroll
        for (int r = 0; r < 16; ++r) {
            h2 u0p = uint_as_h2(R[r].x);
            h2 u1p = uint_as_h2(R[r].y);
            h2 u2p = uint_as_h2(R[r].z);
            h2 u3p = uint_as_h2(R[r].w);
            a0 = fdot2_acc(u0p, E0[4 * r + 0], a0);
            a1 = fdot2_acc(u1p, E0[4 * r + 1], a1);
            a2 = fdot2_acc(u2p, E0[4 * r + 2], a2);
            a3 = fdot2_acc(u3p, E0[4 * r + 3], a3);
            c0 = fdot2_acc(u0p, E1[4 * r + 0], c0);
            c1 = fdot2_acc(u1p, E1[4 * r + 1], c1);
            c2 = fdot2_acc(u2p, E1[4 * r + 2], c2);
            c3 = fdot2_acc(u3p, E1[4 * r + 3], c3);
        }
        float acc0 = (a0 + a1) + (a2 + a3);
        float acc1 = (c0 + c1) + (c2 + c3);

        if (t < T_DIM - 1) {
            float un0 = acc0 * fe0;
            float un1 = acc1 * fe1;
            fa = fb; fb = fnew;
            LdsU[cur ^ 1][p] = __builtin_bit_cast(unsigned int, pack_f16(un0, un1));
            cur ^= 1;
        } else {
            accF0 = acc0; accF1 = acc1;
        }
    }

    S += 510.0f * LOG128;   // folded 1/128 per dot

    // ---- sentence_score = LSE over 128 j (2 per lane) ----
    float x0 = __logf(accF0) + S + trS0;
    float x1 = __logf(accF1) + S + trS1;
    float mx = fmaxf(x0, x1);
#pragma unroll
    for (int d = 1; d < 64; d <<= 1) mx = fmaxf(mx, __shfl_xor(mx, d));
    float ex = __expf(x0 - mx) + __expf(x1 - mx);
#pragma unroll
    for (int d = 1; d < 64; d <<= 1) ex += __shfl_xor(ex, d);
    float sentence = mx + __logf(ex);

    // ---- gold score: 511 terms over 64 lanes ----
    float es = 0.f, ts = 0.f;
#pragma unroll
    for (int k = 0; k < 8; ++k) {
        int t = 1 + lane + (k << 6);
        if (t < T_DIM) {
            int tg = target[b * T_DIM + t];
            es += fbase[t * L_DIM + tg];
            int pr = (t == 1) ? start : target[b * T_DIM + t - 1];
            ts += transfer[pr * L_DIM + tg];
        }
    }
#pragma unroll
    for (int d = 1; d < 64; d <<= 1) {
        es += __shfl_xor(es, d);
        ts += __shfl_xor(ts, d);
    }

    if (lane == 0) {
        float emit0 = fbase[start];          // feats[b, 0, start]
        out[b] = sentence - __expf(emit0 + es + ts);
    }
}

extern "C" void kernel_launch(void* const* d_in, const int* in_sizes, int n_in,
                              void* d_out, int out_size, void* d_ws, size_t ws_size,
                              hipStream_t stream) {
    const float* feats    = (const float*)d_in[0];
    const float* transfer = (const float*)d_in[1];
    const int*   target   = (const int*)d_in[2];
    const int*   startp   = (const int*)d_in[3];
    const int*   stopp    = (const int*)d_in[4];
    float* outp = (float*)d_out;
    int B = in_sizes[0] / (T_DIM * L_DIM);
    hipLaunchKernelGGL(crf_fwd_kernel, dim3(B), dim3(64), 0, stream,
                       feats, transfer, target, startp, stopp, outp);
}

// Round 6
// 397.057 us; speedup vs baseline: 1.0026x; 1.0026x over previous
//
#include <hip/hip_runtime.h>
#include <hip/hip_bf16.h>

#define T_DIM 512
#define L_DIM 128

typedef _Float16 h2 __attribute__((ext_vector_type(2)));

#if defined(__has_builtin)
#if __has_builtin(__builtin_amdgcn_fdot2)
#define HAS_FDOT2 1
#endif
#endif

__device__ __forceinline__ float fdot2_acc(h2 a, h2 b, float c) {
#ifdef HAS_FDOT2
    return __builtin_amdgcn_fdot2(a, b, c, false);
#else
    return c + (float)a.x * (float)b.x + (float)a.y * (float)b.y;
#endif
}

__device__ __forceinline__ h2 pack_f16(float a, float b) {
    return __builtin_bit_cast(h2, __builtin_amdgcn_cvt_pkrtz(a, b));
}

__device__ __forceinline__ h2 uint_as_h2(unsigned int v) {
    return __builtin_bit_cast(h2, v);
}

// ONE WAVE PER CHAIN — no s_barrier in the step loop (wave lockstep +
// s_waitcnt lgkmcnt(0) orders the LDS u-exchange; vmcnt is never drained
// so the feats prefetch stays in flight).
//
// Round-6 fix: round 5 demanded ~230 live VGPRs (E=128 + uint4 R[16]=64
// + misc) against the 256 arch cap -> E spilled to scratch, ~500 cyc of
// L1 latency per step. Now u is consumed in 4 groups of 4 x uint4 (16
// dwords in flight) so live set ~190 and E stays resident in VGPRs.
__global__ __launch_bounds__(64, 1) void crf_fwd_kernel(
    const float* __restrict__ feats,
    const float* __restrict__ transfer,
    const int* __restrict__ target,
    const int* __restrict__ startp,
    const int* __restrict__ stopp,
    float* __restrict__ out)
{
    __shared__ unsigned int LdsU[2][64] __attribute__((aligned(16)));

    const int lane = threadIdx.x;       // owns label pair (2p, 2p+1)
    const int p    = lane;
    const int j0   = p << 1;
    const int b    = blockIdx.x;
    const int start = startp[0];
    const int stop  = stopp[0];
    const float* fbase = feats + (size_t)b * T_DIM * L_DIM;
    const float2* f2 = reinterpret_cast<const float2*>(fbase);
    const float LOG128 = 4.852030263919617f;

    // ---- one-time: both E columns, Ehat = exp(transfer)/128, in regs ----
    h2 E0[64], E1[64];
#pragma unroll
    for (int q = 0; q < 64; ++q) {
        const float2* r0 = reinterpret_cast<const float2*>(transfer + (2 * q) * L_DIM + j0);
        const float2* r1 = reinterpret_cast<const float2*>(transfer + (2 * q + 1) * L_DIM + j0);
        float2 e0 = *r0;   // (tr[2q][j0], tr[2q][j1])
        float2 e1 = *r1;   // (tr[2q+1][j0], tr[2q+1][j1])
        E0[q] = pack_f16(__expf(e0.x) * 0.0078125f, __expf(e1.x) * 0.0078125f);
        E1[q] = pack_f16(__expf(e0.y) * 0.0078125f, __expf(e1.y) * 0.0078125f);
    }
    const float trS0 = transfer[j0 * L_DIM + stop];
    const float trS1 = transfer[(j0 | 1) * L_DIM + stop];

    // ---- init: u = exp(f_1 + tr[start] + f_2) ----
    {
        float2 f1v = f2[1 * 64 + p];
        float2 f2v = f2[2 * 64 + p];
        const float2* ts = reinterpret_cast<const float2*>(transfer + start * L_DIM + j0);
        float2 tsv = *ts;
        LdsU[0][p] = __builtin_bit_cast(unsigned int,
                        pack_f16(__expf(f1v.x + f2v.x + tsv.x),
                                 __expf(f1v.y + f2v.y + tsv.y)));
    }
    float2 fa = f2[3 * 64 + p];   // f_{t+1} consumed at t=2
    float2 fb = f2[4 * 64 + p];
    float S = 0.f;

    int cur = 0;
    float accF0 = 0.f, accF1 = 0.f;

    for (int t = 2; t <= T_DIM - 1; ++t) {
        int tp = t + 3; if (tp > T_DIM - 1) tp = T_DIM - 1;
        float2 fnew = f2[tp * 64 + p];        // stays in flight (no vmcnt drain)
        float fe0 = __expf(fa.x);
        float fe1 = __expf(fa.y);

        // prior-iteration ds_write must be visible before this read
        asm volatile("s_waitcnt lgkmcnt(0)" ::: "memory");
        const uint4* P4 = reinterpret_cast<const uint4*>(&LdsU[cur][0]);

        float a0 = 0.f, a1 = 0.f, a2 = 0.f, a3 = 0.f;
        float c0 = 0.f, c1 = 0.f, c2 = 0.f, c3 = 0.f;
        bool renorm = ((t & 15) == 0);

        // 4 groups of 4 x uint4: only 16 u-dwords live at a time
#pragma unroll
        for (int g = 0; g < 4; ++g) {
            uint4 q0 = P4[4 * g + 0];
            uint4 q1 = P4[4 * g + 1];
            uint4 q2 = P4[4 * g + 2];
            uint4 q3 = P4[4 * g + 3];
            if (g == 0 && renorm) {           // u0 free from the broadcast
                float u0 = (float)uint_as_h2(q0.x).x;
                float rr = __builtin_amdgcn_rcpf(u0);
                S += __logf(u0);
                fe0 *= rr; fe1 *= rr;
            }
#pragma unroll
            for (int r = 0; r < 4; ++r) {
                uint4 qq = (r == 0) ? q0 : (r == 1) ? q1 : (r == 2) ? q2 : q3;
                int e = 16 * g + 4 * r;
                h2 u0p = uint_as_h2(qq.x);
                h2 u1p = uint_as_h2(qq.y);
                h2 u2p = uint_as_h2(qq.z);
                h2 u3p = uint_as_h2(qq.w);
                a0 = fdot2_acc(u0p, E0[e + 0], a0);
                a1 = fdot2_acc(u1p, E0[e + 1], a1);
                a2 = fdot2_acc(u2p, E0[e + 2], a2);
                a3 = fdot2_acc(u3p, E0[e + 3], a3);
                c0 = fdot2_acc(u0p, E1[e + 0], c0);
                c1 = fdot2_acc(u1p, E1[e + 1], c1);
                c2 = fdot2_acc(u2p, E1[e + 2], c2);
                c3 = fdot2_acc(u3p, E1[e + 3], c3);
            }
        }
        float acc0 = (a0 + a1) + (a2 + a3);
        float acc1 = (c0 + c1) + (c2 + c3);

        if (t < T_DIM - 1) {
            float un0 = acc0 * fe0;
            float un1 = acc1 * fe1;
            fa = fb; fb = fnew;
            LdsU[cur ^ 1][p] = __builtin_bit_cast(unsigned int, pack_f16(un0, un1));
            cur ^= 1;
        } else {
            accF0 = acc0; accF1 = acc1;
        }
    }

    S += 510.0f * LOG128;   // folded 1/128 per dot

    // ---- sentence_score = LSE over 128 j (2 per lane) ----
    float x0 = __logf(accF0) + S + trS0;
    float x1 = __logf(accF1) + S + trS1;
    float mx = fmaxf(x0, x1);
#pragma unroll
    for (int d = 1; d < 64; d <<= 1) mx = fmaxf(mx, __shfl_xor(mx, d));
    float ex = __expf(x0 - mx) + __expf(x1 - mx);
#pragma unroll
    for (int d = 1; d < 64; d <<= 1) ex += __shfl_xor(ex, d);
    float sentence = mx + __logf(ex);

    // ---- gold score: 511 terms over 64 lanes ----
    float es = 0.f, ts = 0.f;
#pragma unroll
    for (int k = 0; k < 8; ++k) {
        int t = 1 + lane + (k << 6);
        if (t < T_DIM) {
            int tg = target[b * T_DIM + t];
            es += fbase[t * L_DIM + tg];
            int pr = (t == 1) ? start : target[b * T_DIM + t - 1];
            ts += transfer[pr * L_DIM + tg];
        }
    }
#pragma unroll
    for (int d = 1; d < 64; d <<= 1) {
        es += __shfl_xor(es, d);
        ts += __shfl_xor(ts, d);
    }

    if (lane == 0) {
        float emit0 = fbase[start];          // feats[b, 0, start]
        out[b] = sentence - __expf(emit0 + es + ts);
    }
}

extern "C" void kernel_launch(void* const* d_in, const int* in_sizes, int n_in,
                              void* d_out, int out_size, void* d_ws, size_t ws_size,
                              hipStream_t stream) {
    const float* feats    = (const float*)d_in[0];
    const float* transfer = (const float*)d_in[1];
    const int*   target   = (const int*)d_in[2];
    const int*   startp   = (const int*)d_in[3];
    const int*   stopp    = (const int*)d_in[4];
    float* outp = (float*)d_out;
    int B = in_sizes[0] / (T_DIM * L_DIM);
    hipLaunchKernelGGL(crf_fwd_kernel, dim3(B), dim3(64), 0, stream,
                       feats, transfer, target, startp, stopp, outp);
}